// Round 6
// baseline (195.806 us; speedup 1.0000x reference)
//
#include <hip/hip_runtime.h>
#include <hip/hip_bf16.h>

#define D_DIM 768
#define B_DIM 8192
#define NT 64           // tile grid dim (8192/128)
#define NTILES 2080     // NT*(NT+1)/2 upper-triangle tiles
#define TPX 260         // tiles per XCD counter (2080/8)
#define NBLK 512        // persistent blocks = 2 per CU
#define BM 128

typedef __attribute__((ext_vector_type(8))) short short8;
typedef __attribute__((ext_vector_type(4))) float f32x4;
typedef __attribute__((ext_vector_type(2))) float f32x2;
typedef __attribute__((ext_vector_type(4))) unsigned short ushort4v;

// ws layout (bytes)
#define WS_XB   0                               // bf16[8192*768]   = 12,582,912
#define WS_SQ   12582912                        // float[8192]      = 32,768
#define WS_CAND 12615680                        // float[8192*64*6] = 12,582,912
#define WS_ACC  25198592                        // float[1]
#define WS_TKT  25198596                        // uint[1]
#define WS_CNT  25198624                        // uint[8] per-XCD tile counters

__device__ __forceinline__ void gl_lds16(const void* g, void* lds) {
  __builtin_amdgcn_global_load_lds(
      (const __attribute__((address_space(1))) unsigned int*)g,
      (__attribute__((address_space(3))) unsigned int*)lds, 16, 0, 0);
}

// branchless: maintain v[0..5] = six smallest seen, sorted ascending.
__device__ __forceinline__ void ins6(float c, float* v) {
  v[5] = fminf(v[5], c);
#pragma unroll
  for (int s = 5; s > 0; --s) {
    float lo = fminf(v[s - 1], v[s]);
    float hi = fmaxf(v[s - 1], v[s]);
    v[s - 1] = lo;
    v[s] = hi;
  }
}

// band-blocked triangle order (16x16-tile blocks, rt-major inside): L2 working
// set ~3.3 MB. g in [0,2080). (verbatim from round-4 passing kernel)
__device__ __forceinline__ void tile_decode(int g, int& rt, int& ct) {
  int base = 0;
  for (int s = 0; s < 4; ++s) {
    for (int cb = s; cb < 4; ++cb) {
      const int sz = (cb == s) ? 136 : 256;
      if (g < base + sz) {
        int loc = g - base;
        if (cb == s) {
          int r = 0;
          while (loc >= 16 - r) {
            loc -= 16 - r;
            ++r;
          }
          rt = s * 16 + r;
          ct = cb * 16 + r + loc;
        } else {
          rt = s * 16 + (loc >> 4);
          ct = cb * 16 + (loc & 15);
        }
        return;
      }
      base += sz;
    }
  }
  rt = 0;
  ct = 0;
}

// kernel 1: cast fp32 -> bf16 (vectorized), row sum-of-squares; init counters.
__global__ __launch_bounds__(256) void cast_sq_kernel(
    const float* __restrict__ x, unsigned short* __restrict__ xb,
    float* __restrict__ sq, float* __restrict__ acc,
    unsigned int* __restrict__ tkt, unsigned int* __restrict__ cnt) {
  const int t = threadIdx.x;
  const int w = t >> 6, lane = t & 63;
  const int row = blockIdx.x * 4 + w;
  if (blockIdx.x == 0) {
    if (t < 8) cnt[t] = 0u;
    if (t == 8) acc[0] = 0.0f;
    if (t == 9) tkt[0] = 0u;
  }
  const f32x4* xr = (const f32x4*)(x + (size_t)row * D_DIM);
  ushort4v* xbr = (ushort4v*)(xb + (size_t)row * D_DIM);
  float s = 0.0f;
#pragma unroll
  for (int c = 0; c < 3; ++c) {
    const int idx = c * 64 + lane;
    f32x4 v = xr[idx];
    ushort4v u;
#pragma unroll
    for (int e = 0; e < 4; ++e) {
      __hip_bfloat16 h = __float2bfloat16(v[e]);
      unsigned short us;
      __builtin_memcpy(&us, &h, 2);
      u[e] = us;
      float vb = __bfloat162float(h);
      s += vb * vb;
    }
    xbr[idx] = u;
  }
#pragma unroll
  for (int off = 32; off > 0; off >>= 1) s += __shfl_down(s, off, 64);
  if (lane == 0) sq[row] = s;
}

// ------- kernel 2: persistent symmetric 128x128 Gram, ring-of-4, 2 blocks/CU -------
// Per-XCD atomic counters hand out band-blocked tiles. The gl_lds pipeline never
// drains across tile boundaries: next tile's sections 0,1 are staged during the
// epilogue (into the zone distS does not alias), section 2 at loop top; uniform
// vmcnt(8) in the main loop. ds_read/overwrite safety: each wave's lgkmcnt wait
// before its MFMAs retires all ds_reads of a slot before the barrier that
// precedes restaging that slot.
// ring slots: A0,A1,B0,B1 | A2,A3,B2,B3 (8 x 8KB = 64KB); distS[32][132] aliases
// A2,A3,B2-head (bytes 32768..49792) - untouched by the epilogue prefetch (s0,s1).
#define ASL(k) ((k) < 2 ? (k) * 8192 : 16384 + (k) * 8192)
#define BSL(k) ((k) < 2 ? 16384 + (k) * 8192 : 32768 + (k) * 8192)
#define VMW(N) asm volatile("s_waitcnt vmcnt(" #N ")" ::: "memory")
#define BAR()                         \
  {                                   \
    asm volatile("" ::: "memory");    \
    __builtin_amdgcn_s_barrier();     \
    asm volatile("" ::: "memory");    \
  }

__global__ __launch_bounds__(256, 2) void knn_gemm_kernel(
    const unsigned short* __restrict__ xb, const float* __restrict__ sq,
    float* __restrict__ cand, unsigned int* __restrict__ cnt) {
  __shared__ __align__(16) char smem[65536];
  __shared__ int sN;

  const int t = threadIdx.x;
  const int lane = t & 63, w = t >> 6;
  const int wm = w >> 1, wn = w & 1;  // 2x2 wave grid; wave tile 64x64
  const int quad = lane >> 4, m16 = lane & 15;
  const int xcd = blockIdx.x & 7;
  unsigned int* myCnt = cnt + xcd;

  // staging geometry: thread t -> LDS row R0 (and R0+64), lds seg t&3.
  // swizzle: lds slot (R, s) holds global seg s ^ ((R>>1)&3)
  const int R0 = t >> 2;
  const int sg = (t & 3) ^ ((t >> 3) & 3);
  // fragment read: byte = R*64 + (quad ^ ((R>>1)&3))*16; (R>>1)&3 == (m16>>1)&3
  const int laneOff = ((quad ^ ((m16 >> 1) & 3)) << 4) + m16 * 64;
  const int aOff = wm * 4096 + laneOff;
  const int bOff = wn * 4096 + laneOff;

#define STAGE(P, EOFF, REGION)                                            \
  {                                                                       \
    gl_lds16((P) + (EOFF), smem + (REGION) + t * 16);                     \
    gl_lds16((P) + (EOFF) + 64 * D_DIM, smem + (REGION) + 4096 + t * 16); \
  }

  short8 aF[4], bF[4];
  f32x4 acv[4][4];
#define LDA(BASE)                                                            \
  {                                                                          \
    _Pragma("unroll") for (int ii = 0; ii < 4; ++ii)                         \
        aF[ii] = *(const short8*)(smem + (BASE) + ii * 1024 + aOff);         \
  }
#define LDB(BASE)                                                            \
  {                                                                          \
    _Pragma("unroll") for (int j = 0; j < 4; ++j)                            \
        bF[j] = *(const short8*)(smem + (BASE) + j * 1024 + bOff);           \
  }
#define MFMA16                                                               \
  {                                                                          \
    __builtin_amdgcn_s_setprio(1);                                           \
    _Pragma("unroll") for (int ii = 0; ii < 4; ++ii)                         \
        _Pragma("unroll") for (int j = 0; j < 4; ++j)                        \
            acv[ii][j] = __builtin_amdgcn_mfma_f32_16x16x32_bf16(            \
                aF[ii], bF[j], acv[ii][j], 0, 0, 0);                         \
    __builtin_amdgcn_s_setprio(0);                                           \
  }

  // first tile
  if (t == 0) sN = (int)atomicAdd(myCnt, 1u);
  __syncthreads();
  int idx = sN;
  bool have = idx < TPX;
  int rt = 0, ct = 0;
  if (have) tile_decode(xcd * TPX + idx, rt, ct);
  bool offdiag = (ct > rt);
  const unsigned short* pA = xb + (size_t)(rt * BM + R0) * D_DIM + sg * 8;
  const unsigned short* pB = xb + (size_t)(ct * BM + R0) * D_DIM + sg * 8;
  float rsq[16], csq[4];
  if (have) {
#pragma unroll
    for (int i = 0; i < 4; ++i)
#pragma unroll
      for (int r = 0; r < 4; ++r)
        rsq[i * 4 + r] = sq[rt * BM + wm * 64 + i * 16 + quad * 4 + r];
#pragma unroll
    for (int j = 0; j < 4; ++j) csq[j] = sq[ct * BM + wn * 64 + j * 16 + m16];
    STAGE(pA, 0, ASL(0));
    STAGE(pB, 0, BSL(0));
    STAGE(pA, 32, ASL(1));
    STAGE(pB, 32, BSL(1));
  }

  while (have) {
    STAGE(pA, 64, ASL(2));  // section 2
    STAGE(pB, 64, BSL(2));
    if (t == 0) sN = (int)atomicAdd(myCnt, 1u);  // next tile (read in epilogue)
    const f32x4 zero = {0.0f, 0.0f, 0.0f, 0.0f};
#pragma unroll
    for (int i = 0; i < 4; ++i)
#pragma unroll
      for (int j = 0; j < 4; ++j) acv[i][j] = zero;

    // main loop: 24 sections (BK=32 each), ring-of-4, depth-3 prefetch, VMW(8)
    for (int sb = 0; sb < 5; ++sb) {
#pragma unroll
      for (int i = 0; i < 4; ++i) {
        VMW(8);
        BAR();
        const int ps = sb * 4 + i + 3;
        STAGE(pA, ps * 32, ASL((i + 3) & 3));
        STAGE(pB, ps * 32, BSL((i + 3) & 3));
        LDA(ASL(i));
        LDB(BSL(i));
        MFMA16;
      }
    }
    VMW(8);
    BAR();
    STAGE(pA, 23 * 32, ASL(3));  // s=20 stages s23
    STAGE(pB, 23 * 32, BSL(3));
    LDA(ASL(0));
    LDB(BSL(0));
    MFMA16;
    VMW(8);
    BAR();
    LDA(ASL(1));
    LDB(BSL(1));
    MFMA16;
    VMW(4);
    BAR();
    LDA(ASL(2));
    LDB(BSL(2));
    MFMA16;
    VMW(0);
    BAR();
    LDA(ASL(3));
    LDB(BSL(3));
    MFMA16;

    // ---------------- epilogue (4 groups of 32 rows) ----------------
    const int nidx = sN;
    const bool nhave = nidx < TPX;
    int nrt = 0, nct = 0;
    if (nhave) tile_decode(xcd * TPX + nidx, nrt, nct);
    const unsigned short* npA = xb + (size_t)(nrt * BM + R0) * D_DIM + sg * 8;
    const unsigned short* npB = xb + (size_t)(nct * BM + R0) * D_DIM + sg * 8;

    BAR();  // all waves done with ring data (lgkm retired per-wave pre-barrier)
    if (nhave) {  // next tile s0,s1 -> zone untouched by distS
      STAGE(npA, 0, ASL(0));
      STAGE(npB, 0, BSL(0));
      STAGE(npA, 32, ASL(1));
      STAGE(npB, 32, BSL(1));
    }
    float nrsq[16], ncsq[4];
    if (nhave) {
#pragma unroll
      for (int i = 0; i < 4; ++i)
#pragma unroll
        for (int r = 0; r < 4; ++r)
          nrsq[i * 4 + r] = sq[nrt * BM + wm * 64 + i * 16 + quad * 4 + r];
#pragma unroll
      for (int j = 0; j < 4; ++j)
        ncsq[j] = sq[nct * BM + wn * 64 + j * 16 + m16];
    }

    float* distS = (float*)(smem + 32768);  // [32][132]
    float* rsqS = (float*)(smem + 49664);   // [32]
    float colrun[6];
#pragma unroll
    for (int q = 0; q < 6; ++q) colrun[q] = 1e30f;

#pragma unroll
    for (int g = 0; g < 4; ++g) {
      if (g) BAR();
      if (wm == (g >> 1)) {
        const int i0 = (g & 1) * 2;
        // row-key = csq[col] - 2G (row-constant rsq added at write)
#pragma unroll
        for (int ii = 0; ii < 2; ++ii)
#pragma unroll
          for (int j = 0; j < 4; ++j)
#pragma unroll
            for (int r = 0; r < 4; ++r)
              distS[(ii * 16 + quad * 4 + r) * 132 + wn * 64 + j * 16 + m16] =
                  csq[j] - 2.0f * acv[i0 + ii][j][r];
        if (wn == 0 && m16 == 0) {
#pragma unroll
          for (int ii = 0; ii < 2; ++ii)
#pragma unroll
            for (int r = 0; r < 4; ++r)
              rsqS[ii * 16 + quad * 4 + r] = rsq[(i0 + ii) * 4 + r];
        }
      }
      BAR();
      // row select: 8 thr/row x 16 cols, rotated chunks
      const int row_l = t >> 3, sub = t & 7;
      const float* drow = distS + row_l * 132 + sub * 16;
      float v[6];
#pragma unroll
      for (int q = 0; q < 6; ++q) v[q] = 1e30f;
#pragma unroll
      for (int k = 0; k < 4; ++k) {
        f32x4 dv = *(const f32x4*)(drow + ((k + sub) & 3) * 4);
        ins6(dv[0], v);
        ins6(dv[1], v);
        ins6(dv[2], v);
        ins6(dv[3], v);
      }
#pragma unroll
      for (int st = 1; st <= 4; st <<= 1) {
        float o[6];
#pragma unroll
        for (int q = 0; q < 6; ++q) o[q] = __shfl_xor(v[q], st, 64);
#pragma unroll
        for (int q = 0; q < 6; ++q) ins6(o[q], v);
      }
      if (sub == 0) {
        const int grow = rt * BM + g * 32 + row_l;
        const float rq = rsqS[row_l];
        float* o = cand + (size_t)(grow * NT + ct) * 6;
        f32x2 w0 = {fmaxf(v[0] + rq, 0.0f), fmaxf(v[1] + rq, 0.0f)};
        f32x2 w1 = {fmaxf(v[2] + rq, 0.0f), fmaxf(v[3] + rq, 0.0f)};
        f32x2 w2 = {fmaxf(v[4] + rq, 0.0f), fmaxf(v[5] + rq, 0.0f)};
        *(f32x2*)o = w0;
        *(f32x2*)(o + 2) = w1;
        *(f32x2*)(o + 4) = w2;
      }
      // column partial (off-diagonal only): key = distS + rsq[row] = full d^2
      if (offdiag) {
        const int col = t >> 1, h = t & 1;
#pragma unroll
        for (int k = 0; k < 16; ++k) {
          const int r = h * 16 + k;
          ins6(distS[r * 132 + col] + rsqS[r], colrun);
        }
      }
    }
    if (offdiag) {
      float o2[6];
#pragma unroll
      for (int q = 0; q < 6; ++q) o2[q] = __shfl_xor(colrun[q], 1, 64);
#pragma unroll
      for (int q = 0; q < 6; ++q) ins6(o2[q], colrun);
      if ((t & 1) == 0) {
        const int colg = ct * BM + (t >> 1);
        float* o = cand + (size_t)(colg * NT + rt) * 6;
        f32x2 w0 = {fmaxf(colrun[0], 0.0f), fmaxf(colrun[1], 0.0f)};
        f32x2 w1 = {fmaxf(colrun[2], 0.0f), fmaxf(colrun[3], 0.0f)};
        f32x2 w2 = {fmaxf(colrun[4], 0.0f), fmaxf(colrun[5], 0.0f)};
        *(f32x2*)o = w0;
        *(f32x2*)(o + 2) = w1;
        *(f32x2*)(o + 4) = w2;
      }
    }
    // advance to next tile
    if (nhave) {
      rt = nrt;
      ct = nct;
      offdiag = (nct > nrt);
      pA = npA;
      pB = npB;
#pragma unroll
      for (int i = 0; i < 16; ++i) rsq[i] = nrsq[i];
#pragma unroll
      for (int j = 0; j < 4; ++j) csq[j] = ncsq[j];
    }
    have = nhave;
    BAR();  // protect distS reads before next loop-top STAGE into A2/B2
  }
}

// kernel 3: per-row merge of 64 chunk-candidates -> sqrt -> log -> global sum,
// with fused finalize via ticket (last block writes the output).
__global__ __launch_bounds__(256) void knn_merge_kernel(
    const float* __restrict__ cand, float* __restrict__ acc,
    unsigned int* __restrict__ tkt, float* __restrict__ out) {
  const int t = threadIdx.x;
  const int r = blockIdx.x * 32 + (t >> 3);
  const float* cr = cand + (size_t)r * (NT * 6) + (size_t)(t & 7) * 48;
  float v[6];
#pragma unroll
  for (int s = 0; s < 6; ++s) v[s] = 1e30f;
#pragma unroll
  for (int c = 0; c < 12; ++c) {
    f32x4 dv = *(const f32x4*)(cr + c * 4);
    ins6(dv[0], v);
    ins6(dv[1], v);
    ins6(dv[2], v);
    ins6(dv[3], v);
  }
#pragma unroll
  for (int st = 1; st <= 4; st <<= 1) {
    float o[6];
#pragma unroll
    for (int q = 0; q < 6; ++q) o[q] = __shfl_xor(v[q], st, 64);
#pragma unroll
    for (int q = 0; q < 6; ++q) ins6(o[q], v);
  }
  float term = 0.0f;
  if ((t & 7) == 0) {
    // v sorted ascending on d^2: v[0] = self (0); knn_mean = mean of sqrt(v[1..5])
    const float mean =
        (sqrtf(v[1]) + sqrtf(v[2]) + sqrtf(v[3]) + sqrtf(v[4]) + sqrtf(v[5])) * 0.2f;
    term = logf(mean + 1e-8f);
  }
#pragma unroll
  for (int off = 32; off > 0; off >>= 1) term += __shfl_down(term, off, 64);
  __shared__ float red[4];
  if ((t & 63) == 0) red[t >> 6] = term;
  __syncthreads();
  if (t == 0) {
    atomicAdd(acc, red[0] + red[1] + red[2] + red[3]);
    __threadfence();
    const unsigned int tk = atomicAdd(tkt, 1u);
    if (tk == (B_DIM / 32) - 1) {
      const float total = atomicAdd(acc, 0.0f);  // coherent read of final sum
      out[0] = -total * (1.0f / 8192.0f);
    }
  }
}

extern "C" void kernel_launch(void* const* d_in, const int* in_sizes, int n_in,
                              void* d_out, int out_size, void* d_ws, size_t ws_size,
                              hipStream_t stream) {
  const float* x = (const float*)d_in[0];
  float* out = (float*)d_out;
  char* ws = (char*)d_ws;
  unsigned short* xb = (unsigned short*)(ws + WS_XB);
  float* sq = (float*)(ws + WS_SQ);
  float* cand = (float*)(ws + WS_CAND);
  float* acc = (float*)(ws + WS_ACC);
  unsigned int* tkt = (unsigned int*)(ws + WS_TKT);
  unsigned int* cnt = (unsigned int*)(ws + WS_CNT);

  cast_sq_kernel<<<B_DIM / 4, 256, 0, stream>>>(x, xb, sq, acc, tkt, cnt);
  knn_gemm_kernel<<<NBLK, 256, 0, stream>>>(xb, sq, cand, cnt);
  knn_merge_kernel<<<B_DIM / 32, 256, 0, stream>>>(cand, acc, tkt, out);
}